// Round 11
// baseline (193.117 us; speedup 1.0000x reference)
//
#include <hip/hip_runtime.h>
#include <hip/hip_bf16.h>

// VQ-VAE VectorQuantizer — round 16: in-wave pipelined screen.
//   r10 finding: screen dur == SUM of pipe budgets (LDS 22 + VALU 16 + MFMA 14
//   + HBM 7 ≈ 59 µs) — zero inter-pipe overlap. Cause: 1-deep ds_read prefetch
//   (each MFMA stalls ~86 cyc on its A-frag) + top3 fully serialized after
//   each chunk's MFMA chain.
//   k_screen12 = r10's k_screen11 with the sweep rewritten as a flat 136-step
//   pipeline per quarter: 4-deep rotating A-frag prefetch + acc ping-pong so
//   chunk c-1's 16 top3-inserts interleave 1:1 between chunk c's MFMAs.
//   accPrev init = +inf (packed u always loses) -> no first-chunk branch.
//   Staging layout / fused resolve / k_prep2 / k_epi4 unchanged (passing).

#define EMBED_DIM 256
#define N_EMBED   1024
#define HW        4096
#define NPIX      65536
#define BETA      0.25f
#define SBIAS     1024.0f
#define TAU       0.375f

typedef _Float16 h8v __attribute__((ext_vector_type(8)));
typedef __attribute__((ext_vector_type(16))) float f32x16;

// ---------------- workspace layout (float offsets) ----------------
#define NW_ES2T   64              // 34816 h8v = 139264 floats
#define NW_WIDXT  139328          // u16[65536] = 32768 floats
#define NW_EMBTT  172096          // 256*1024 floats
#define NW_ENDT   434240
#define NEEDT_BYTES ((size_t)NW_ENDT * 4)

// fallback (round-1) layout
#define WS_ET_OFF    64
#define WS_NORM_OFF  (64 + EMBED_DIM * N_EMBED)

#define QUART_BYTES (136 * 1024)  // 8 chunks x 17 frags x 1 KB

__device__ inline void async16(const void* g, void* s) {
    __builtin_amdgcn_global_load_lds(
        (const __attribute__((address_space(1))) unsigned int*)g,
        (__attribute__((address_space(3))) unsigned int*)s, 16, 0, 0);
}

__device__ inline unsigned umin2(unsigned a, unsigned b) { return a < b ? a : b; }
__device__ inline unsigned umax2(unsigned a, unsigned b) { return a < b ? b : a; }

// sorted top-3 insert on packed (score|idx) — pure min/max network (5 ops)
__device__ inline void top3_ins(unsigned u, unsigned& b1, unsigned& b2, unsigned& b3) {
    unsigned t0 = umax2(b1, u);  b1 = umin2(b1, u);
    unsigned t1 = umax2(b2, t0); b2 = umin2(b2, t0);
    b3 = umin2(b3, t1);
}

// ======================= prep kernel =======================
// blocks 0..135   : es2 frag t = (akb*32 + cb)*64 + lane ; akb 16 = norm kb
//                   (||e||^2 + SBIAS as fp16 hi/lo in k=0,1).
// blocks 136..1159: embT[c][j] = emb[j][c] (coalesced reads).

__global__ void k_prep2(const float* __restrict__ emb, _Float16* __restrict__ es2,
                        float* __restrict__ embT, float* __restrict__ out_loss) {
    if (blockIdx.x < 136) {
        int t = blockIdx.x * 256 + threadIdx.x;       // 0..34815
        if (t == 0) *out_loss = 0.f;
        int lane = t & 63;
        int cb   = (t >> 6) & 31;
        int akb  = t >> 11;                           // 0..16
        int m = cb * 32 + (lane & 31);
        int h = lane >> 5;
        _Float16 o[8];
        if (akb < 16) {
            #pragma unroll
            for (int j = 0; j < 8; ++j) {
                int c = akb * 16 + h * 8 + j;
                o[j] = (_Float16)(-2.0f * emb[m * EMBED_DIM + c]);
            }
        } else {
            #pragma unroll
            for (int j = 0; j < 8; ++j) o[j] = (_Float16)0.f;
            if (h == 0) {                             // inline norm
                const float4* row = (const float4*)(emb + (size_t)m * EMBED_DIM);
                float nm = SBIAS;
                #pragma unroll 8
                for (int r = 0; r < 64; ++r) {
                    float4 v = row[r];
                    nm += v.x * v.x + v.y * v.y + v.z * v.z + v.w * v.w;
                }
                _Float16 nh = (_Float16)nm;
                _Float16 nl = (_Float16)(nm - (float)nh);
                o[0] = nh; o[1] = nl;
            }
        }
        *(h8v*)(es2 + (size_t)t * 8) = *(h8v*)o;
    } else {
        int t2 = (blockIdx.x - 136) * 256 + threadIdx.x;   // 0..262143
        int c = t2 & 255;                                  // coalesced read
        int j = t2 >> 8;
        embT[(size_t)c * N_EMBED + j] = emb[(size_t)j * EMBED_DIM + c];
    }
}

// ======================= screen kernel (in-wave pipelined) =======================
// 512 threads (8 waves), 256 px/block, grid 256 (1 block/CU). LDS holds a
// QUARTER of the codebook (136 KB), staged 4x in-place. Per quarter: flat
// 136-step pipeline (4-deep A-frag prefetch; prev-chunk top3 interleaved).

__global__ __launch_bounds__(512, 2)
void k_screen12(const float* __restrict__ z, const float* __restrict__ emb,
                const _Float16* __restrict__ es2,
                unsigned short* __restrict__ widx, float* __restrict__ out_loss) {
    __shared__ __align__(16) char abuf[QUART_BYTES];   // 136 KB (1 block/CU)
    __shared__ float wsum[8];

    const int tid  = threadIdx.x;
    const int lane = tid & 63;
    const int wv   = tid >> 6;                    // 0..7
    const int pxl  = lane & 31;
    const int h    = lane >> 5;
    const int ln16 = lane * 16;

    // stage quarter 0: 136 frags, 17 per wave. frag (ch,f) <- es2 code-chunk
    // (q*8+ch), akb f ; LDS offset (ch*17+f)*1024.
    {
        for (int i = 0; i < 17; ++i) {
            const int fg = wv + i * 8;                 // 0..135
            if (fg < 136) {
                const int ch = fg / 17, f = fg % 17;
                const _Float16* src = es2 + ((size_t)(f * 32 + ch) * 64 + lane) * 8;
                async16(src, abuf + (ch * 17 + f) * 1024 + ln16);
            }
        }
    }

    // build B fragments (hi-only fp16) straight from z; accumulate ||x||^2
    const int wb = blockIdx.x * 256 + wv * 32;    // wave's first px
    const int px = wb + pxl;
    const float* zb = z + (size_t)(px >> 12) * (EMBED_DIM * HW) + (px & 4095);

    float nx = 0.f;
    h8v bx[16];
    #pragma unroll
    for (int kh = 0; kh < 16; ++kh) {
        const int c0 = kh * 16 + h * 8;
        _Float16 oh[8];
        #pragma unroll
        for (int j = 0; j < 8; ++j) {
            float v = zb[(size_t)(c0 + j) * HW];
            nx += v * v;
            oh[j] = (_Float16)v;
        }
        bx[kh] = *(h8v*)oh;
    }
    nx += __shfl_xor(nx, 32, 64);                 // full ||x||^2 on both halves

    h8v bn;                                       // norm-kb B: B[0..1][n] = 1
    #pragma unroll
    for (int j = 0; j < 8; ++j) bn[j] = (_Float16)0.f;
    if (lane < 32) { bn[0] = (_Float16)1.f; bn[1] = (_Float16)1.f; }

    const unsigned maskc = 0xFFFFFC00u;
    unsigned b1 = 0xFFFFFFFFu, b2 = 0xFFFFFFFFu, b3 = 0xFFFFFFFFu;

    // acc ping-pong: chunk ch computes accBuf[ch&1], inserts accBuf[(ch&1)^1]
    // (prev chunk). Init "prev" = +inf so chunk -1's inserts always lose.
    f32x16 accBuf[2];
    #pragma unroll
    for (int r = 0; r < 16; ++r) accBuf[1][r] = __uint_as_float(0x7F800000u);
    unsigned jbPrev = 0;

    __syncthreads();                              // quarter-0 staging complete

    for (int q = 0; q < 4; ++q) {
        // 4-deep rotating prefetch buffer (all indices static after unroll)
        h8v a[4];
        #pragma unroll
        for (int i = 0; i < 4; ++i)
            a[i] = *(const h8v*)(abuf + i * 1024 + ln16);

        #pragma unroll
        for (int ch = 0; ch < 8; ++ch) {
            const int cur = ch & 1, prv = cur ^ 1;
            #pragma unroll
            for (int r = 0; r < 16; ++r) accBuf[cur][r] = 0.f;
            const unsigned jbCur = (unsigned)((q * 8 + ch) * 32 + h * 4);

            #pragma unroll
            for (int k = 0; k < 17; ++k) {
                const int g = ch * 17 + k;
                const h8v af = a[g & 3];
                if (g + 4 < 136)                  // issue 4 ahead
                    a[(g + 4) & 3] = *(const h8v*)(abuf + (g + 4) * 1024 + ln16);
                accBuf[cur] = __builtin_amdgcn_mfma_f32_32x32x16_f16(
                                  af, (k < 16) ? bx[k] : bn, accBuf[cur], 0, 0, 0);
                if (k < 16) {                     // prev-chunk top3, 1:1 interleave
                    const unsigned idx = jbPrev + (unsigned)((k & 3) + 8 * (k >> 2));
                    unsigned u = (__float_as_uint(accBuf[prv][k]) & maskc) | idx;
                    top3_ins(u, b1, b2, b3);
                }
            }
            jbPrev = jbCur;
        }

        // ---- restage in place for next quarter ----
        if (q < 3) {
            __syncthreads();                      // all waves done reading
            for (int i = 0; i < 17; ++i) {
                const int fg = wv + i * 8;
                if (fg < 136) {
                    const int ch = fg / 17, f = fg % 17;
                    const _Float16* src = es2 +
                        ((size_t)(f * 32 + (q + 1) * 8 + ch) * 64 + lane) * 8;
                    async16(src, abuf + (ch * 17 + f) * 1024 + ln16);
                }
            }
            __syncthreads();                      // staging complete
        }
    }

    // epilogue: top3 of the final chunk (ch=31 lives in accBuf[1])
    #pragma unroll
    for (int k = 0; k < 16; ++k) {
        const unsigned idx = jbPrev + (unsigned)((k & 3) + 8 * (k >> 2));
        unsigned u = (__float_as_uint(accBuf[1][k]) & maskc) | idx;
        top3_ins(u, b1, b2, b3);
    }

    // merge the two k-row halves (lane^32 holds the other 16 rows)
    {
        unsigned o1 = __shfl_xor(b1, 32, 64);
        unsigned o2 = __shfl_xor(b2, 32, 64);
        unsigned o3 = __shfl_xor(b3, 32, 64);
        top3_ins(o1, b1, b2, b3);
        top3_ins(o2, b1, b2, b3);
        top3_ins(o3, b1, b2, b3);
    }

    // fused resolve: lane l (<32) owns px wb+l
    const float s1 = __uint_as_float(b1 & maskc);
    const float s2 = __uint_as_float(b2 & maskc);
    int   j  = (int)(b1 & 1023u);
    const int j2 = (int)(b2 & 1023u);
    const int j3 = (int)(b3 & 1023u);
    float d  = s1 - SBIAS + nx;                   // screen-accurate distance

    unsigned long long fm = __ballot(lane < 32 && (s2 - s1 < TAU));
    if (fm) {
        while (fm) {
            const int l = __ffsll(fm) - 1;        // l < 32
            fm &= fm - 1;
            const int fj1 = __shfl(j, l, 64);
            const int fj2 = __shfl(j2, l, 64);
            const int fj3 = __shfl(j3, l, 64);
            const int fpx = wb + l;
            const float* zp = z + (size_t)(fpx >> 12) * (EMBED_DIM * HW) + (fpx & 4095);
            const int cc0 = lane * 4;
            const float4 e1 = *(const float4*)(emb + (size_t)fj1 * EMBED_DIM + cc0);
            const float4 e2 = *(const float4*)(emb + (size_t)fj2 * EMBED_DIM + cc0);
            const float4 e3 = *(const float4*)(emb + (size_t)fj3 * EMBED_DIM + cc0);
            float d1 = 0.f, d2 = 0.f, d3 = 0.f;
            #pragma unroll
            for (int k = 0; k < 4; ++k) {
                const float zv = zp[(size_t)(cc0 + k) * HW];
                float t1 = ((const float*)&e1)[k] - zv; d1 += t1 * t1;
                float t2 = ((const float*)&e2)[k] - zv; d2 += t2 * t2;
                float t3 = ((const float*)&e3)[k] - zv; d3 += t3 * t3;
            }
            #pragma unroll
            for (int off = 32; off; off >>= 1) {
                d1 += __shfl_xor(d1, off, 64);
                d2 += __shfl_xor(d2, off, 64);
                d3 += __shfl_xor(d3, off, 64);
            }
            int bj = fj1; float bd = d1;
            if (d2 < bd || (d2 == bd && fj2 < bj)) { bd = d2; bj = fj2; }
            if (d3 < bd || (d3 == bd && fj3 < bj)) { bd = d3; bj = fj3; }
            if (lane == l) { j = bj; d = bd; }
        }
    }

    if (lane < 32) widx[wb + lane] = (unsigned short)j;

    float ls = (lane < 32) ? d : 0.f;
    #pragma unroll
    for (int off = 32; off; off >>= 1) ls += __shfl_xor(ls, off, 64);
    if (lane == 0) wsum[wv] = ls;
    __syncthreads();
    if (tid == 0) {
        float t = 0.f;
        #pragma unroll
        for (int w = 0; w < 8; ++w) t += wsum[w];
        atomicAdd(out_loss, t * (BETA / (float)NPIX / (float)EMBED_DIM));
    }
}

// ======================= streaming epilogue =======================
// One wave per out row (b,c). embT row staged into LDS; random gathers hit
// LDS banks instead of serializing in L1. Contiguous 16 KB stores.

__global__ __launch_bounds__(256)
void k_epi4(const float* __restrict__ embT, const unsigned short* __restrict__ widx,
            float* __restrict__ out) {
    __shared__ float etl[4][N_EMBED];             // 16 KB
    const int tid  = threadIdx.x;
    const int lane = tid & 63;
    const int wv   = tid >> 6;
    const int rowid = blockIdx.x * 4 + wv;        // 0..4095
    const int b = rowid >> 8;
    const int c = rowid & 255;

    const unsigned short* wb = widx + b * HW;
    const float4* et4 = (const float4*)(embT + (size_t)c * N_EMBED);
    float* ob = out + (size_t)b * (EMBED_DIM * HW) + (size_t)c * HW;

    #pragma unroll
    for (int i = 0; i < 4; ++i)                   // wave-private row stage
        *(float4*)&etl[wv][(lane + i * 64) * 4] = et4[lane + i * 64];

    #pragma unroll 4
    for (int t = 0; t < 16; ++t) {
        const int hw = t * 256 + lane * 4;
        const ushort4 jj = *(const ushort4*)(wb + hw);
        float4 v;
        v.x = etl[wv][jj.x];
        v.y = etl[wv][jj.y];
        v.z = etl[wv][jj.z];
        v.w = etl[wv][jj.w];
        *(float4*)(ob + hw) = v;
    }
}

// ======================= fallback (round-1 fp32 path) =======================

__global__ void k_norms(const float* __restrict__ emb, float* __restrict__ norms,
                        float* __restrict__ loss_acc) {
    int j = blockIdx.x;
    int lane = threadIdx.x;
    const float* row = emb + j * EMBED_DIM;
    float s = 0.f;
    #pragma unroll
    for (int r = 0; r < 4; ++r) { float v = row[lane + r * 64]; s += v * v; }
    #pragma unroll
    for (int off = 32; off; off >>= 1) s += __shfl_down(s, off, 64);
    if (lane == 0) norms[j] = s;
    if (blockIdx.x == 0 && lane == 0) loss_acc[0] = 0.f;
}

__global__ void k_final(const float* __restrict__ loss_acc, float* __restrict__ out_loss) {
    *out_loss = (BETA / (float)NPIX / (float)EMBED_DIM) * (*loss_acc);
}

__global__ void k_transpose(const float* __restrict__ emb, float* __restrict__ et) {
    int idx = blockIdx.x * blockDim.x + threadIdx.x;
    int c = idx >> 10;
    int j = idx & 1023;
    et[idx] = -2.0f * emb[j * EMBED_DIM + c];
}

__global__ __launch_bounds__(256, 2)
void k_vq(const float* __restrict__ z, const float* __restrict__ emb,
          const float* __restrict__ et, const float* __restrict__ norms,
          float* __restrict__ out, float* __restrict__ loss_acc)
{
    __shared__ float zt[EMBED_DIM * 64];
    __shared__ float redv[16 * 64];
    __shared__ int   redi[16 * 64];
    __shared__ int   widx[64];
    __shared__ float wsum[4];
    const int tid = threadIdx.x;
    const int wg  = blockIdx.x;
    const int p0  = wg * 64;
    const int b   = p0 >> 12;
    const int hw0 = p0 & 4095;
    const float* zbase = z + (size_t)b * (EMBED_DIM * HW) + hw0;
    {
        const int lane16 = tid & 15;
        const int crow   = tid >> 4;
        #pragma unroll
        for (int r = 0; r < 16; ++r) {
            int c = r * 16 + crow;
            float4 vv = *(const float4*)(zbase + (size_t)c * HW + lane16 * 4);
            *(float4*)&zt[c * 64 + lane16 * 4] = vv;
        }
    }
    __syncthreads();
    const int pxg = tid & 15;
    const int cg  = tid >> 4;
    float bestv[4] = {3.4e38f, 3.4e38f, 3.4e38f, 3.4e38f};
    int   besti[4] = {0, 0, 0, 0};
    for (int chunk = 0; chunk < 16; ++chunk) {
        const int jbase = chunk * 64 + cg * 4;
        float acc[4][4];
        #pragma unroll
        for (int i = 0; i < 4; ++i)
            #pragma unroll
            for (int k = 0; k < 4; ++k) acc[i][k] = 0.f;
        const float* ec = et + jbase;
        #pragma unroll 4
        for (int c = 0; c < EMBED_DIM; ++c) {
            float4 za = *(const float4*)&zt[c * 64 + pxg * 4];
            float4 eb = *(const float4*)(ec + (size_t)c * N_EMBED);
            float zi[4] = {za.x, za.y, za.z, za.w};
            float ek[4] = {eb.x, eb.y, eb.z, eb.w};
            #pragma unroll
            for (int i = 0; i < 4; ++i)
                #pragma unroll
                for (int k = 0; k < 4; ++k)
                    acc[i][k] += zi[i] * ek[k];
        }
        float nn[4];
        #pragma unroll
        for (int k = 0; k < 4; ++k) nn[k] = norms[jbase + k];
        #pragma unroll
        for (int i = 0; i < 4; ++i)
            #pragma unroll
            for (int k = 0; k < 4; ++k) {
                float s = nn[k] + acc[i][k];
                if (s < bestv[i]) { bestv[i] = s; besti[i] = jbase + k; }
            }
    }
    #pragma unroll
    for (int i = 0; i < 4; ++i) {
        redv[cg * 64 + pxg * 4 + i] = bestv[i];
        redi[cg * 64 + pxg * 4 + i] = besti[i];
    }
    __syncthreads();
    if (tid < 64) {
        const int px2 = tid;
        float bv = redv[px2];
        int   bi = redi[px2];
        #pragma unroll
        for (int g = 1; g < 16; ++g) {
            float vv = redv[g * 64 + px2];
            int   ix = redi[g * 64 + px2];
            if (vv < bv || (vv == bv && ix < bi)) { bv = vv; bi = ix; }
        }
        widx[px2] = bi;
    }
    __syncthreads();
    const int px = tid & 63;
    const int wv = tid >> 6;
    const int j  = widx[px];
    const float* qrow = emb + (size_t)j * EMBED_DIM;
    float* obase = out + (size_t)b * (EMBED_DIM * HW) + hw0;
    float lsum = 0.f;
    #pragma unroll 4
    for (int cc = 0; cc < 16; ++cc) {
        const int c0 = wv * 64 + cc * 4;
        float4 q = *(const float4*)(qrow + c0);
        float qv[4] = {q.x, q.y, q.z, q.w};
        #pragma unroll
        for (int k = 0; k < 4; ++k) {
            const int c = c0 + k;
            float zv = zt[c * 64 + px];
            float d = qv[k] - zv;
            lsum += d * d;
            obase[(size_t)c * HW + px] = qv[k];
        }
    }
    #pragma unroll
    for (int off = 32; off; off >>= 1) lsum += __shfl_down(lsum, off, 64);
    if ((tid & 63) == 0) wsum[wv] = lsum;
    __syncthreads();
    if (tid == 0) atomicAdd(loss_acc, wsum[0] + wsum[1] + wsum[2] + wsum[3]);
}

// ======================= launch =======================

extern "C" void kernel_launch(void* const* d_in, const int* in_sizes, int n_in,
                              void* d_out, int out_size, void* d_ws, size_t ws_size,
                              hipStream_t stream) {
    const float* z   = (const float*)d_in[0];
    const float* emb = (const float*)d_in[1];
    float* out       = (float*)d_out;
    float* ws        = (float*)d_ws;

    if (ws_size >= NEEDT_BYTES) {
        _Float16*       es2      = (_Float16*)(ws + NW_ES2T);
        unsigned short* widx     = (unsigned short*)(ws + NW_WIDXT);
        float*          embT     = ws + NW_EMBTT;
        float*          out_loss = out + (size_t)NPIX * EMBED_DIM;

        k_prep2<<<1160, 256, 0, stream>>>(emb, es2, embT, out_loss);
        k_screen12<<<256, 512, 0, stream>>>(z, emb, es2, widx, out_loss);
        k_epi4<<<1024, 256, 0, stream>>>(embT, widx, out);
    } else {
        float* loss_acc = ws;
        float* et       = ws + WS_ET_OFF;
        float* norms    = ws + WS_NORM_OFF;
        k_transpose<<<(EMBED_DIM * N_EMBED) / 256, 256, 0, stream>>>(emb, et);
        k_norms<<<N_EMBED, 64, 0, stream>>>(emb, norms, loss_acc);
        k_vq<<<NPIX / 64, 256, 0, stream>>>(z, emb, et, norms, out, loss_acc);
        k_final<<<1, 1, 0, stream>>>(loss_acc, out + (size_t)NPIX * EMBED_DIM);
    }
}